// Round 1
// baseline (1436.489 us; speedup 1.0000x reference)
//
#include <hip/hip_runtime.h>

#define NUM_CLUSTERS 50000

// Monotonic unsigned mapping of f32: preserves order, atomicMax-able.
__device__ __forceinline__ unsigned fkey(float f) {
    unsigned b = __float_as_uint(f);
    return b ^ ((b & 0x80000000u) ? 0xFFFFFFFFu : 0x80000000u);
}
__device__ __forceinline__ float funkey(unsigned k) {
    unsigned b = (k & 0x80000000u) ? (k ^ 0x80000000u) : ~k;
    return __uint_as_float(b);
}

// One thread = one node. Weights are lane-uniform -> scalar loads (SGPRs).
__global__ __launch_bounds__(256) void mlp_segmax_kernel(
    const float* __restrict__ x, const int* __restrict__ cluster,
    const float* __restrict__ W1, const float* __restrict__ b1,
    const float* __restrict__ ln_g, const float* __restrict__ ln_b,
    const float* __restrict__ W2, const float* __restrict__ b2,
    float* __restrict__ out, unsigned* __restrict__ aggr, int N)
{
    int n = blockIdx.x * 256 + threadIdx.x;
    if (n >= N) return;

    float h[64];
    #pragma unroll
    for (int j = 0; j < 64; ++j) h[j] = b1[j];

    // h = x[n] @ W1 + b1 ; x row loaded as float4, 4 x-values per iteration.
    const float4* xp = (const float4*)(x + (size_t)n * 64);
    for (int ii = 0; ii < 16; ++ii) {
        float4 xv = xp[ii];
        const float* w = W1 + ii * 4 * 64;   // uniform base -> s_load
        #pragma unroll
        for (int j = 0; j < 64; ++j) {
            h[j] = fmaf(xv.x, w[j],       h[j]);
            h[j] = fmaf(xv.y, w[64 + j],  h[j]);
            h[j] = fmaf(xv.z, w[128 + j], h[j]);
            h[j] = fmaf(xv.w, w[192 + j], h[j]);
        }
    }

    // LayerNorm over the 64 h-values (per-thread, all static indices).
    float mu = 0.f;
    #pragma unroll
    for (int j = 0; j < 64; ++j) mu += h[j];
    mu *= (1.f / 64.f);
    float var = 0.f;
    #pragma unroll
    for (int j = 0; j < 64; ++j) { float d = h[j] - mu; var = fmaf(d, d, var); }
    var *= (1.f / 64.f);
    float rs = rsqrtf(var + 1e-5f);

    // affine + SiLU
    #pragma unroll
    for (int j = 0; j < 64; ++j) {
        float t = (h[j] - mu) * rs * ln_g[j] + ln_b[j];
        h[j] = t / (1.f + __expf(-t));
    }

    // out = h @ W2 + b2
    float o[32];
    #pragma unroll
    for (int k = 0; k < 32; ++k) o[k] = b2[k];
    #pragma unroll
    for (int j = 0; j < 64; ++j) {
        float hv = h[j];
        #pragma unroll
        for (int k = 0; k < 32; ++k) o[k] = fmaf(hv, W2[j * 32 + k], o[k]);
    }

    // store first 32 columns of the output row
    float4* op = (float4*)(out + (size_t)n * 64);
    #pragma unroll
    for (int q = 0; q < 8; ++q)
        op[q] = make_float4(o[4*q], o[4*q+1], o[4*q+2], o[4*q+3]);

    // segment max via unsigned-key atomicMax
    int c = cluster[n];
    unsigned* ag = aggr + (size_t)c * 32;
    #pragma unroll
    for (int k = 0; k < 32; ++k) atomicMax(ag + k, fkey(o[k]));
}

// Element-per-thread gather: out[n, 32+k] = decode(aggr[cluster[n], k])
__global__ __launch_bounds__(256) void gather_kernel(
    const int* __restrict__ cluster, const unsigned* __restrict__ aggr,
    float* __restrict__ out, int N)
{
    long long idx = (long long)blockIdx.x * 256 + threadIdx.x;
    if (idx >= (long long)N * 32) return;
    int n = (int)(idx >> 5);
    int k = (int)(idx & 31);
    int c = cluster[n];
    out[(size_t)n * 64 + 32 + k] = funkey(aggr[(size_t)c * 32 + k]);
}

extern "C" void kernel_launch(void* const* d_in, const int* in_sizes, int n_in,
                              void* d_out, int out_size, void* d_ws, size_t ws_size,
                              hipStream_t stream) {
    const float* x    = (const float*)d_in[0];
    const int* cluster = (const int*)d_in[1];
    // d_in[2] = batch (unused by the reference output)
    const float* W1   = (const float*)d_in[3];
    const float* b1   = (const float*)d_in[4];
    const float* ln_g = (const float*)d_in[5];
    const float* ln_b = (const float*)d_in[6];
    const float* W2   = (const float*)d_in[7];
    const float* b2   = (const float*)d_in[8];
    float* out = (float*)d_out;
    unsigned* aggr = (unsigned*)d_ws;

    int N = in_sizes[0] / 64;

    // init segment-max keys to 0 (== smaller than any real value's key)
    hipMemsetAsync(aggr, 0, (size_t)NUM_CLUSTERS * 32 * sizeof(unsigned), stream);

    int blocks1 = (N + 255) / 256;
    mlp_segmax_kernel<<<blocks1, 256, 0, stream>>>(
        x, cluster, W1, b1, ln_g, ln_b, W2, b2, out, aggr, N);

    long long total2 = (long long)N * 32;
    int blocks2 = (int)((total2 + 255) / 256);
    gather_kernel<<<blocks2, 256, 0, stream>>>(cluster, aggr, out, N);
}

// Round 2
// 595.254 us; speedup vs baseline: 2.4132x; 2.4132x over previous
//
#include <hip/hip_runtime.h>

#define NUM_CLUSTERS 50000

// Monotonic unsigned mapping of f32: preserves order, atomicMax-able.
__device__ __forceinline__ unsigned fkey(float f) {
    unsigned b = __float_as_uint(f);
    return b ^ ((b & 0x80000000u) ? 0xFFFFFFFFu : 0x80000000u);
}
__device__ __forceinline__ float funkey(unsigned k) {
    unsigned b = (k & 0x80000000u) ? (k ^ 0x80000000u) : ~k;
    return __uint_as_float(b);
}
__device__ __forceinline__ unsigned short f2bf(float f) {  // RNE
    unsigned u = __float_as_uint(f);
    return (unsigned short)((u + 0x7FFFu + ((u >> 16) & 1u)) >> 16);
}

// Block = 256 threads = 256 nodes. x staged coalesced->LDS(bf16, XOR-swizzled
// granules); per-thread MLP in registers with SGPR-streamed weights; o-tile
// staged back in the SAME LDS (own-row overwrite, no barrier needed); then
// coalesced stores + transposed atomics (32 lanes = one node's aggr row).
__global__ __launch_bounds__(256) void mlp_segmax_kernel(
    const float* __restrict__ x, const int* __restrict__ cluster,
    const float* __restrict__ W1, const float* __restrict__ b1,
    const float* __restrict__ ln_g, const float* __restrict__ ln_b,
    const float* __restrict__ W2, const float* __restrict__ b2,
    float* __restrict__ out, unsigned* __restrict__ aggr, int N)
{
    __shared__ char smem[256 * 128];   // 32 KB, unioned: bf16 x-tile then f32 o-tile
    const int t = threadIdx.x;
    const long long nodeBase = (long long)blockIdx.x * 256;
    const long long NElem = (long long)N * 64;

    // ---- Phase 1: coalesced x load (f32) -> bf16 LDS, swizzled 16B granules
    #pragma unroll 4
    for (int p = 0; p < 16; ++p) {
        int le = (p * 256 + t) * 4;                 // local elem 0..16383
        long long e = nodeBase * 64 + le;
        if (e < NElem) {
            float4 v = *(const float4*)(x + e);
            int row = le >> 6;                      // local node
            int k = le & 63;
            int g = k >> 3;                         // 16B granule (8 bf16)
            int half = (k >> 2) & 1;
            int phys = row * 128 + ((g ^ (row & 7)) << 4) + (half << 3);
            ushort4 b;
            b.x = f2bf(v.x); b.y = f2bf(v.y); b.z = f2bf(v.z); b.w = f2bf(v.w);
            *(ushort4*)(smem + phys) = b;
        }
    }
    __syncthreads();

    // ---- Phase 2: per-thread MLP (node = nodeBase + t)
    const bool active = (nodeBase + t) < N;
    if (active) {
        float h[64];
        #pragma unroll
        for (int j = 0; j < 64; ++j) h[j] = b1[j];

        #pragma unroll 1
        for (int g = 0; g < 8; ++g) {
            uint4 raw = *(const uint4*)(smem + t * 128 + ((g ^ (t & 7)) << 4));
            float xk[8];
            xk[0] = __uint_as_float(raw.x << 16);
            xk[1] = __uint_as_float(raw.x & 0xffff0000u);
            xk[2] = __uint_as_float(raw.y << 16);
            xk[3] = __uint_as_float(raw.y & 0xffff0000u);
            xk[4] = __uint_as_float(raw.z << 16);
            xk[5] = __uint_as_float(raw.z & 0xffff0000u);
            xk[6] = __uint_as_float(raw.w << 16);
            xk[7] = __uint_as_float(raw.w & 0xffff0000u);
            const float* w = W1 + g * 8 * 64;       // lane-uniform -> s_load
            #pragma unroll
            for (int kk = 0; kk < 8; ++kk) {
                #pragma unroll
                for (int j = 0; j < 64; ++j)
                    h[j] = fmaf(xk[kk], w[kk * 64 + j], h[j]);
            }
        }

        // LayerNorm (per-thread, static indices)
        float mu = 0.f;
        #pragma unroll
        for (int j = 0; j < 64; ++j) mu += h[j];
        mu *= (1.f / 64.f);
        float var = 0.f;
        #pragma unroll
        for (int j = 0; j < 64; ++j) { float d = h[j] - mu; var = fmaf(d, d, var); }
        var *= (1.f / 64.f);
        float rs = rsqrtf(var + 1e-5f);
        #pragma unroll
        for (int j = 0; j < 64; ++j) {
            float v = (h[j] - mu) * rs * ln_g[j] + ln_b[j];
            h[j] = v / (1.f + __expf(-v));          // SiLU
        }

        // GEMM2: o = h @ W2 + b2
        float o[32];
        #pragma unroll
        for (int k = 0; k < 32; ++k) o[k] = b2[k];
        #pragma unroll 8
        for (int j = 0; j < 64; ++j) {
            float hv = h[j];
            #pragma unroll
            for (int k = 0; k < 32; ++k) o[k] = fmaf(hv, W2[j * 32 + k], o[k]);
        }

        // stage own o row into the SAME LDS region (f32, swizzled float4 granules)
        #pragma unroll
        for (int g = 0; g < 8; ++g) {
            float4 v = make_float4(o[4*g], o[4*g+1], o[4*g+2], o[4*g+3]);
            *(float4*)(smem + t * 128 + ((g ^ (t & 7)) << 4)) = v;
        }
    }
    __syncthreads();

    // ---- Phase 3: coalesced store of out[:, 0:32]
    #pragma unroll 2
    for (int p = 0; p < 8; ++p) {
        int le = (p * 256 + t) * 4;                 // 0..8191
        int row = le >> 5;
        int c = le & 31;
        long long node = nodeBase + row;
        if (node < N) {
            int g = c >> 2;
            float4 v = *(const float4*)(smem + row * 128 + ((g ^ (row & 7)) << 4));
            *(float4*)(out + node * 64 + c) = v;
        }
    }

    // ---- Phase 4: transposed segment-max atomics (32 lanes = 1 node row)
    #pragma unroll 1
    for (int p = 0; p < 32; ++p) {
        int le = p * 256 + t;                       // 0..8191
        int row = le >> 5;
        int c = le & 31;
        long long node = nodeBase + row;
        if (node < N) {
            int g = c >> 2;
            float v = *(const float*)(smem + row * 128 + ((g ^ (row & 7)) << 4) + (c & 3) * 4);
            int cl = cluster[node];
            atomicMax(aggr + (long long)cl * 32 + c, fkey(v));
        }
    }
}

// Element-per-thread gather: out[n, 32+k] = decode(aggr[cluster[n], k])
__global__ __launch_bounds__(256) void gather_kernel(
    const int* __restrict__ cluster, const unsigned* __restrict__ aggr,
    float* __restrict__ out, int N)
{
    long long idx = (long long)blockIdx.x * 256 + threadIdx.x;
    if (idx >= (long long)N * 32) return;
    int n = (int)(idx >> 5);
    int k = (int)(idx & 31);
    int c = cluster[n];
    out[(size_t)n * 64 + 32 + k] = funkey(aggr[(size_t)c * 32 + k]);
}

extern "C" void kernel_launch(void* const* d_in, const int* in_sizes, int n_in,
                              void* d_out, int out_size, void* d_ws, size_t ws_size,
                              hipStream_t stream) {
    const float* x     = (const float*)d_in[0];
    const int* cluster = (const int*)d_in[1];
    // d_in[2] = batch (unused by the reference output)
    const float* W1    = (const float*)d_in[3];
    const float* b1    = (const float*)d_in[4];
    const float* ln_g  = (const float*)d_in[5];
    const float* ln_b  = (const float*)d_in[6];
    const float* W2    = (const float*)d_in[7];
    const float* b2    = (const float*)d_in[8];
    float* out = (float*)d_out;
    unsigned* aggr = (unsigned*)d_ws;

    int N = in_sizes[0] / 64;

    hipMemsetAsync(aggr, 0, (size_t)NUM_CLUSTERS * 32 * sizeof(unsigned), stream);

    int blocks1 = (N + 255) / 256;
    mlp_segmax_kernel<<<blocks1, 256, 0, stream>>>(
        x, cluster, W1, b1, ln_g, ln_b, W2, b2, out, aggr, N);

    long long total2 = (long long)N * 32;
    int blocks2 = (int)((total2 + 255) / 256);
    gather_kernel<<<blocks2, 256, 0, stream>>>(cluster, aggr, out, N);
}

// Round 3
// 339.876 us; speedup vs baseline: 4.2265x; 1.7514x over previous
//
#include <hip/hip_runtime.h>

#define NUM_CLUSTERS 50000

typedef __attribute__((ext_vector_type(8))) short bfx8;
typedef __attribute__((ext_vector_type(4))) float f32x4;

// Monotonic unsigned mapping of f32: preserves order, atomicMax-able.
__device__ __forceinline__ unsigned fkey(float f) {
    unsigned b = __float_as_uint(f);
    return b ^ ((b & 0x80000000u) ? 0xFFFFFFFFu : 0x80000000u);
}
__device__ __forceinline__ float funkey(unsigned k) {
    unsigned b = (k & 0x80000000u) ? (k ^ 0x80000000u) : ~k;
    return __uint_as_float(b);
}
__device__ __forceinline__ unsigned short f2bf(float f) {  // RNE
    unsigned u = __float_as_uint(f);
    return (unsigned short)((u + 0x7FFFu + ((u >> 16) & 1u)) >> 16);
}

// One-time per-launch weight repack into MFMA B-fragment order (bf16).
// B-frag for mfma_f32_16x16x32_bf16: lane holds B[k0..k0+7][col],
// col = 16*ct + (lane&15), k0 = kb*32 + (lane>>4)*8.
__global__ __launch_bounds__(256) void prep_weights(
    const float* __restrict__ W1, const float* __restrict__ W2,
    unsigned short* __restrict__ w1f, unsigned short* __restrict__ w2f)
{
    int tid = blockIdx.x * 256 + threadIdx.x;
    if (tid < 512) {                       // W1: 4 col-tiles x 2 k-frags
        int frag = tid >> 6, lane = tid & 63;
        int ct = frag >> 1, kb = frag & 1;
        int col = ct * 16 + (lane & 15);
        int k0 = kb * 32 + (lane >> 4) * 8;
        #pragma unroll
        for (int i = 0; i < 8; ++i)
            w1f[(frag * 64 + lane) * 8 + i] = f2bf(W1[(k0 + i) * 64 + col]);
    } else if (tid < 768) {                // W2: 2 col-tiles x 2 k-frags
        int frag = (tid - 512) >> 6, lane = tid & 63;
        int ct = frag >> 1, kb = frag & 1;
        int col = ct * 16 + (lane & 15);
        int k0 = kb * 32 + (lane >> 4) * 8;
        #pragma unroll
        for (int i = 0; i < 8; ++i)
            w2f[(frag * 64 + lane) * 8 + i] = f2bf(W2[(k0 + i) * 32 + col]);
    }
}

// Block = 256 threads = 256 nodes, 4 waves; wave w owns nodes [w*64, w*64+64).
// x staged coalesced->LDS bf16 (XOR-swizzled 16B granules = A-frag order);
// GEMM1 via MFMA; LN+SiLU on C-layout with width-16 shuffles; h->LDS bf16
// (own rows, wave-ordered DS => no barrier); GEMM2 via MFMA; o->LDS f32;
// coalesced stores + stale-read-filtered segment-max atomics.
__global__ __launch_bounds__(256) void mlp_segmax_kernel(
    const float* __restrict__ x, const int* __restrict__ cluster,
    const unsigned short* __restrict__ w1f, const float* __restrict__ b1,
    const float* __restrict__ ln_g, const float* __restrict__ ln_b,
    const unsigned short* __restrict__ w2f, const float* __restrict__ b2,
    float* __restrict__ out, unsigned* __restrict__ aggr, int N)
{
    __shared__ char smem[256 * 128];   // 32 KB, unioned: x(bf16) -> h(bf16) -> o(f32)
    const int t = threadIdx.x;
    const int lane = t & 63;
    const int w = t >> 6;
    const int l15 = lane & 15;
    const int q = lane >> 4;
    const long long nodeBase = (long long)blockIdx.x * 256;
    const long long NElem = (long long)N * 64;

    // ---- Phase 1: coalesced x load (f32) -> bf16 LDS, swizzled 16B granules
    #pragma unroll 4
    for (int p = 0; p < 16; ++p) {
        int le = (p * 256 + t) * 4;                 // local elem 0..16383
        long long e = nodeBase * 64 + le;
        if (e < NElem) {
            float4 v = *(const float4*)(x + e);
            int row = le >> 6;                      // local node
            int k = le & 63;
            int g = k >> 3;                         // 16B granule (8 bf16)
            int half = (k >> 2) & 1;
            int phys = row * 128 + ((g ^ (row & 7)) << 4) + (half << 3);
            ushort4 b;
            b.x = f2bf(v.x); b.y = f2bf(v.y); b.z = f2bf(v.z); b.w = f2bf(v.w);
            *(ushort4*)(smem + phys) = b;
        }
    }

    // weight fragments (lane-indexed, L2-hot, reused across all 4 groups)
    bfx8 W1F[4][2], W2F[2][2];
    #pragma unroll
    for (int ct = 0; ct < 4; ++ct)
        #pragma unroll
        for (int kb = 0; kb < 2; ++kb)
            W1F[ct][kb] = *(const bfx8*)(w1f + ((ct * 2 + kb) * 64 + lane) * 8);
    #pragma unroll
    for (int ct = 0; ct < 2; ++ct)
        #pragma unroll
        for (int kb = 0; kb < 2; ++kb)
            W2F[ct][kb] = *(const bfx8*)(w2f + ((ct * 2 + kb) * 64 + lane) * 8);

    // per-lane column params (col = 16*tt + l15)
    float g4[4], bb4[4], b1c[4];
    #pragma unroll
    for (int tt = 0; tt < 4; ++tt) {
        g4[tt]  = ln_g[16 * tt + l15];
        bb4[tt] = ln_b[16 * tt + l15];
        b1c[tt] = b1[16 * tt + l15];
    }
    float b2c[2] = { b2[l15], b2[16 + l15] };

    __syncthreads();

    // ---- Phase 2: per-wave MFMA MLP over 4 node-groups of 16
    #pragma unroll 1
    for (int g = 0; g < 4; ++g) {
        const int base = w * 64 + g * 16;
        const int arow = base + l15;                // A-frag row for this lane
        const int arsw = arow & 7;

        // A-frags from x-LDS: lane reads x[arow][k0..k0+7], k0 = kb*32+q*8
        bfx8 af[2];
        #pragma unroll
        for (int kb = 0; kb < 2; ++kb) {
            int gran = kb * 4 + q;                  // granule = k0*2/16
            af[kb] = *(const bfx8*)(smem + arow * 128 + ((gran ^ arsw) << 4));
        }

        // GEMM1: acc[tt] covers cols 16tt..16tt+15, rows base..base+15
        f32x4 acc[4];
        #pragma unroll
        for (int tt = 0; tt < 4; ++tt) {
            float b = b1c[tt];
            acc[tt] = (f32x4){b, b, b, b};
        }
        #pragma unroll
        for (int kb = 0; kb < 2; ++kb)
            #pragma unroll
            for (int tt = 0; tt < 4; ++tt)
                acc[tt] = __builtin_amdgcn_mfma_f32_16x16x32_bf16(af[kb], W1F[tt][kb], acc[tt], 0, 0, 0);

        // LayerNorm: C-layout row r lives in 16 lanes of quarter q (rows q*4+r)
        float s[4];
        #pragma unroll
        for (int r = 0; r < 4; ++r)
            s[r] = acc[0][r] + acc[1][r] + acc[2][r] + acc[3][r];
        #pragma unroll
        for (int m = 1; m < 16; m <<= 1)
            #pragma unroll
            for (int r = 0; r < 4; ++r) s[r] += __shfl_xor(s[r], m, 16);
        float mu[4];
        #pragma unroll
        for (int r = 0; r < 4; ++r) mu[r] = s[r] * (1.f / 64.f);
        float v[4] = {0.f, 0.f, 0.f, 0.f};
        #pragma unroll
        for (int tt = 0; tt < 4; ++tt)
            #pragma unroll
            for (int r = 0; r < 4; ++r) {
                float d = acc[tt][r] - mu[r];
                v[r] = fmaf(d, d, v[r]);
            }
        #pragma unroll
        for (int m = 1; m < 16; m <<= 1)
            #pragma unroll
            for (int r = 0; r < 4; ++r) v[r] += __shfl_xor(v[r], m, 16);
        float rs[4];
        #pragma unroll
        for (int r = 0; r < 4; ++r) rs[r] = rsqrtf(v[r] * (1.f / 64.f) + 1e-5f);

        // affine + SiLU, pack bf16, write h rows (own rows -> no barrier)
        #pragma unroll
        for (int tt = 0; tt < 4; ++tt)
            #pragma unroll
            for (int r = 0; r < 4; ++r) {
                float val = (acc[tt][r] - mu[r]) * rs[r] * g4[tt] + bb4[tt];
                val = val / (1.f + __expf(-val));   // SiLU
                int node = base + q * 4 + r;
                int col = 16 * tt + l15;
                int gran = col >> 3;
                int phys = node * 128 + ((gran ^ (node & 7)) << 4) + ((col & 7) * 2);
                *(unsigned short*)(smem + phys) = f2bf(val);
            }

        // GEMM2 A-frags from h-LDS (same wave wrote them; DS is wave-ordered)
        bfx8 hf[2];
        #pragma unroll
        for (int kb = 0; kb < 2; ++kb) {
            int gran = kb * 4 + q;
            hf[kb] = *(const bfx8*)(smem + arow * 128 + ((gran ^ arsw) << 4));
        }
        f32x4 oacc[2];
        #pragma unroll
        for (int c = 0; c < 2; ++c) {
            float b = b2c[c];
            oacc[c] = (f32x4){b, b, b, b};
        }
        #pragma unroll
        for (int kb = 0; kb < 2; ++kb)
            #pragma unroll
            for (int c = 0; c < 2; ++c)
                oacc[c] = __builtin_amdgcn_mfma_f32_16x16x32_bf16(hf[kb], W2F[c][kb], oacc[c], 0, 0, 0);

        // o -> LDS f32 [node][32], swizzled 16B granules (own rows)
        #pragma unroll
        for (int c = 0; c < 2; ++c)
            #pragma unroll
            for (int r = 0; r < 4; ++r) {
                int node = base + q * 4 + r;
                int col = c * 16 + l15;             // 0..31
                int byte = col * 4;
                int gran = byte >> 4;
                int phys = node * 128 + ((gran ^ (node & 7)) << 4) + (byte & 15);
                *(float*)(smem + phys) = oacc[c][r];
            }
    }
    __syncthreads();

    // ---- Phase 3: coalesced store of out[:, 0:32]
    #pragma unroll 2
    for (int p = 0; p < 8; ++p) {
        int le = (p * 256 + t) * 4;                 // f32 elem in [256][32]
        int row = le >> 5;
        int c = le & 31;                            // multiple of 4
        long long node = nodeBase + row;
        if (node < N) {
            int gran = c >> 2;
            float4 v4 = *(const float4*)(smem + row * 128 + ((gran ^ (row & 7)) << 4));
            *(float4*)(out + node * 64 + c) = v4;
        }
    }

    // ---- Phase 4: stale-read-filtered segment-max atomics.
    // Safe: values only grow within a launch, so any stale read <= current;
    // skipping when stale >= candidate implies current >= candidate.
    #pragma unroll 1
    for (int p = 0; p < 32; ++p) {
        int le = p * 256 + t;
        int row = le >> 5;
        int c = le & 31;
        long long node = nodeBase + row;
        if (node < N) {
            int gran = c >> 2;
            float v = *(const float*)(smem + row * 128 + ((gran ^ (row & 7)) << 4) + (c & 3) * 4);
            unsigned key = fkey(v);
            int cl = cluster[node];
            unsigned* slot = aggr + (long long)cl * 32 + c;
            if (key > *slot) atomicMax(slot, key);
        }
    }
}

// Element-per-thread gather: out[n, 32+k] = decode(aggr[cluster[n], k])
__global__ __launch_bounds__(256) void gather_kernel(
    const int* __restrict__ cluster, const unsigned* __restrict__ aggr,
    float* __restrict__ out, int N)
{
    long long idx = (long long)blockIdx.x * 256 + threadIdx.x;
    if (idx >= (long long)N * 32) return;
    int n = (int)(idx >> 5);
    int k = (int)(idx & 31);
    int c = cluster[n];
    out[(size_t)n * 64 + 32 + k] = funkey(aggr[(size_t)c * 32 + k]);
}

extern "C" void kernel_launch(void* const* d_in, const int* in_sizes, int n_in,
                              void* d_out, int out_size, void* d_ws, size_t ws_size,
                              hipStream_t stream) {
    const float* x     = (const float*)d_in[0];
    const int* cluster = (const int*)d_in[1];
    // d_in[2] = batch (unused by the reference output)
    const float* W1    = (const float*)d_in[3];
    const float* b1    = (const float*)d_in[4];
    const float* ln_g  = (const float*)d_in[5];
    const float* ln_b  = (const float*)d_in[6];
    const float* W2    = (const float*)d_in[7];
    const float* b2    = (const float*)d_in[8];
    float* out = (float*)d_out;

    unsigned* aggr = (unsigned*)d_ws;                           // 6.4 MB
    unsigned short* w1f = (unsigned short*)((char*)d_ws + (size_t)NUM_CLUSTERS * 32 * 4);
    unsigned short* w2f = w1f + 8 * 64 * 8;                     // +8 KB, then +4 KB

    int N = in_sizes[0] / 64;

    hipMemsetAsync(aggr, 0, (size_t)NUM_CLUSTERS * 32 * sizeof(unsigned), stream);
    prep_weights<<<3, 256, 0, stream>>>(W1, W2, w1f, w2f);

    int blocks1 = (N + 255) / 256;
    mlp_segmax_kernel<<<blocks1, 256, 0, stream>>>(
        x, cluster, w1f, b1, ln_g, ln_b, w2f, b2, out, aggr, N);

    long long total2 = (long long)N * 32;
    int blocks2 = (int)((total2 + 255) / 256);
    gather_kernel<<<blocks2, 256, 0, stream>>>(cluster, aggr, out, N);
}

// Round 4
// 293.661 us; speedup vs baseline: 4.8916x; 1.1574x over previous
//
#include <hip/hip_runtime.h>

#define NUM_CLUSTERS 50000

typedef __attribute__((ext_vector_type(8))) short bfx8;
typedef __attribute__((ext_vector_type(4))) float f32x4;

// Monotonic unsigned mapping of f32: preserves order, atomicMax-able.
__device__ __forceinline__ unsigned fkey(float f) {
    unsigned b = __float_as_uint(f);
    return b ^ ((b & 0x80000000u) ? 0xFFFFFFFFu : 0x80000000u);
}
__device__ __forceinline__ float funkey(unsigned k) {
    unsigned b = (k & 0x80000000u) ? (k ^ 0x80000000u) : ~k;
    return __uint_as_float(b);
}
__device__ __forceinline__ unsigned short f2bf(float f) {  // RNE
    unsigned u = __float_as_uint(f);
    return (unsigned short)((u + 0x7FFFu + ((u >> 16) & 1u)) >> 16);
}

// One-time per-launch weight repack into MFMA B-fragment order (bf16).
// B-frag for mfma_f32_16x16x32_bf16: lane holds B[k0..k0+7][col],
// col = 16*ct + (lane&15), k0 = kb*32 + (lane>>4)*8.
__global__ __launch_bounds__(256) void prep_weights(
    const float* __restrict__ W1, const float* __restrict__ W2,
    unsigned short* __restrict__ w1f, unsigned short* __restrict__ w2f)
{
    int tid = blockIdx.x * 256 + threadIdx.x;
    if (tid < 512) {                       // W1: 4 col-tiles x 2 k-frags
        int frag = tid >> 6, lane = tid & 63;
        int ct = frag >> 1, kb = frag & 1;
        int col = ct * 16 + (lane & 15);
        int k0 = kb * 32 + (lane >> 4) * 8;
        #pragma unroll
        for (int i = 0; i < 8; ++i)
            w1f[(frag * 64 + lane) * 8 + i] = f2bf(W1[(k0 + i) * 64 + col]);
    } else if (tid < 768) {                // W2: 2 col-tiles x 2 k-frags
        int frag = (tid - 512) >> 6, lane = tid & 63;
        int ct = frag >> 1, kb = frag & 1;
        int col = ct * 16 + (lane & 15);
        int k0 = kb * 32 + (lane >> 4) * 8;
        #pragma unroll
        for (int i = 0; i < 8; ++i)
            w2f[(frag * 64 + lane) * 8 + i] = f2bf(W2[(k0 + i) * 32 + col]);
    }
}

// Block = 256 threads = 4 INDEPENDENT waves (no __syncthreads anywhere).
// Wave w owns nodes [blockBase + w*64, +64) and an 8 KB LDS quadrant.
// Stage x coalesced->bf16 LDS (XOR-swizzled 16B granules = A-frag order);
// per 16-node group: MFMA GEMM1 -> LN+SiLU (width-16 shuffles) -> h back to
// own LDS rows (wave-ordered DS, no barrier) -> MFMA GEMM2 -> stores +
// batched stale-read-filtered segment-max atomics, all from registers.
__global__ __launch_bounds__(256, 5) void mlp_segmax_kernel(
    const float* __restrict__ x, const int* __restrict__ cluster,
    const unsigned short* __restrict__ w1f, const float* __restrict__ b1,
    const float* __restrict__ ln_g, const float* __restrict__ ln_b,
    const unsigned short* __restrict__ w2f, const float* __restrict__ b2,
    float* __restrict__ out, unsigned* __restrict__ aggr, int N)
{
    __shared__ char smem[256 * 128];       // 4 waves x 8 KB quadrants
    const int t = threadIdx.x;
    const int lane = t & 63;
    const int w = t >> 6;
    const int l15 = lane & 15;
    const int q = lane >> 4;
    const long long wbase = (long long)blockIdx.x * 256 + w * 64;  // first node of wave
    if (wbase >= N) return;                // whole-wave early exit (N % 64 == 0)
    char* wmem = smem + w * 8192;

    // ---- Stage: wave-private coalesced x load -> bf16 LDS (swizzled granules)
    #pragma unroll 4
    for (int p = 0; p < 16; ++p) {
        int le = (p * 64 + lane) * 4;      // elem 0..4095 within wave tile
        float4 v = *(const float4*)(x + wbase * 64 + le);
        int row = le >> 6;                 // 0..63
        int k = le & 63;
        int g = k >> 3;
        int half = (k >> 2) & 1;
        int phys = row * 128 + ((g ^ (row & 7)) << 4) + (half << 3);
        ushort4 b;
        b.x = f2bf(v.x); b.y = f2bf(v.y); b.z = f2bf(v.z); b.w = f2bf(v.w);
        *(ushort4*)(wmem + phys) = b;
    }

    // weight fragments (lane-indexed, L2-hot, reused across all 4 groups)
    bfx8 W1F[4][2], W2F[2][2];
    #pragma unroll
    for (int ct = 0; ct < 4; ++ct)
        #pragma unroll
        for (int kb = 0; kb < 2; ++kb)
            W1F[ct][kb] = *(const bfx8*)(w1f + ((ct * 2 + kb) * 64 + lane) * 8);
    #pragma unroll
    for (int ct = 0; ct < 2; ++ct)
        #pragma unroll
        for (int kb = 0; kb < 2; ++kb)
            W2F[ct][kb] = *(const bfx8*)(w2f + ((ct * 2 + kb) * 64 + lane) * 8);

    // per-lane column params (col = 16*tt + l15)
    float g4[4], bb4[4], b1c[4];
    #pragma unroll
    for (int tt = 0; tt < 4; ++tt) {
        g4[tt]  = ln_g[16 * tt + l15];
        bb4[tt] = ln_b[16 * tt + l15];
        b1c[tt] = b1[16 * tt + l15];
    }
    float b2c[2] = { b2[l15], b2[16 + l15] };

    // ---- 4 groups of 16 nodes
    #pragma unroll 1
    for (int g = 0; g < 4; ++g) {
        const int base = g * 16;           // local row base
        const int arow = base + l15;
        const int arsw = arow & 7;

        // A-frags: lane reads x[arow][k0..k0+7], k0 = kb*32 + q*8
        bfx8 af[2];
        #pragma unroll
        for (int kb = 0; kb < 2; ++kb)
            af[kb] = *(const bfx8*)(wmem + arow * 128 + (((kb * 4 + q) ^ arsw) << 4));

        // GEMM1
        f32x4 acc[4];
        #pragma unroll
        for (int tt = 0; tt < 4; ++tt) {
            float b = b1c[tt];
            acc[tt] = (f32x4){b, b, b, b};
        }
        #pragma unroll
        for (int kb = 0; kb < 2; ++kb)
            #pragma unroll
            for (int tt = 0; tt < 4; ++tt)
                acc[tt] = __builtin_amdgcn_mfma_f32_16x16x32_bf16(af[kb], W1F[tt][kb], acc[tt], 0, 0, 0);

        // LayerNorm: row q*4+r lives in the 16 lanes of quarter q
        float s[4];
        #pragma unroll
        for (int r = 0; r < 4; ++r)
            s[r] = acc[0][r] + acc[1][r] + acc[2][r] + acc[3][r];
        #pragma unroll
        for (int m = 1; m < 16; m <<= 1)
            #pragma unroll
            for (int r = 0; r < 4; ++r) s[r] += __shfl_xor(s[r], m, 16);
        float mu[4];
        #pragma unroll
        for (int r = 0; r < 4; ++r) mu[r] = s[r] * (1.f / 64.f);
        float vv[4] = {0.f, 0.f, 0.f, 0.f};
        #pragma unroll
        for (int tt = 0; tt < 4; ++tt)
            #pragma unroll
            for (int r = 0; r < 4; ++r) {
                float d = acc[tt][r] - mu[r];
                vv[r] = fmaf(d, d, vv[r]);
            }
        #pragma unroll
        for (int m = 1; m < 16; m <<= 1)
            #pragma unroll
            for (int r = 0; r < 4; ++r) vv[r] += __shfl_xor(vv[r], m, 16);
        float rs[4];
        #pragma unroll
        for (int r = 0; r < 4; ++r) rs[r] = rsqrtf(vv[r] * (1.f / 64.f) + 1e-5f);

        // affine + SiLU, pack bf16, write h rows (own wave's rows, DS in-order)
        #pragma unroll
        for (int tt = 0; tt < 4; ++tt)
            #pragma unroll
            for (int r = 0; r < 4; ++r) {
                float val = (acc[tt][r] - mu[r]) * rs[r] * g4[tt] + bb4[tt];
                val = val / (1.f + __expf(-val));   // SiLU
                int node = base + q * 4 + r;
                int col = 16 * tt + l15;
                int phys = node * 128 + ((((col >> 3)) ^ (node & 7)) << 4) + ((col & 7) * 2);
                *(unsigned short*)(wmem + phys) = f2bf(val);
            }

        // GEMM2 A-frags from h (same rows, same wave -> ordered)
        bfx8 hf[2];
        #pragma unroll
        for (int kb = 0; kb < 2; ++kb)
            hf[kb] = *(const bfx8*)(wmem + arow * 128 + (((kb * 4 + q) ^ arsw) << 4));
        f32x4 oacc[2];
        #pragma unroll
        for (int c = 0; c < 2; ++c) {
            float b = b2c[c];
            oacc[c] = (f32x4){b, b, b, b};
        }
        #pragma unroll
        for (int kb = 0; kb < 2; ++kb)
            #pragma unroll
            for (int c = 0; c < 2; ++c)
                oacc[c] = __builtin_amdgcn_mfma_f32_16x16x32_bf16(hf[kb], W2F[c][kb], oacc[c], 0, 0, 0);

        // ---- Epilogue from registers: stores + batched filtered atomics.
        // Lane's element (c,r): node = wbase + base + q*4 + r, col = c*16 + l15.
        int clr[4];
        #pragma unroll
        for (int r = 0; r < 4; ++r)
            clr[r] = cluster[wbase + base + q * 4 + r];

        unsigned keys[8];
        unsigned* slots[8];
        #pragma unroll
        for (int c = 0; c < 2; ++c)
            #pragma unroll
            for (int r = 0; r < 4; ++r) {
                int i = c * 4 + r;
                float v = oacc[c][r];
                long long node = wbase + base + q * 4 + r;
                out[node * 64 + c * 16 + l15] = v;
                keys[i] = fkey(v);
                slots[i] = aggr + (long long)clr[r] * 32 + c * 16 + l15;
            }
        unsigned olds[8];
        #pragma unroll
        for (int i = 0; i < 8; ++i) olds[i] = *slots[i];   // batched, in flight
        #pragma unroll
        for (int i = 0; i < 8; ++i)
            if (keys[i] > olds[i]) atomicMax(slots[i], keys[i]);
    }
}

// Gather: thread handles 4 cols -> out[n, 32+4k..] = decode(aggr[cluster[n]])
__global__ __launch_bounds__(256) void gather_kernel(
    const int* __restrict__ cluster, const unsigned* __restrict__ aggr,
    float* __restrict__ out, int N)
{
    long long idx = (long long)blockIdx.x * 256 + threadIdx.x;
    if (idx >= (long long)N * 8) return;
    int n = (int)(idx >> 3);
    int k4 = (int)(idx & 7) * 4;
    int c = cluster[n];
    uint4 a = *(const uint4*)(aggr + (size_t)c * 32 + k4);
    float4 o;
    o.x = funkey(a.x); o.y = funkey(a.y); o.z = funkey(a.z); o.w = funkey(a.w);
    *(float4*)(out + (size_t)n * 64 + 32 + k4) = o;
}

extern "C" void kernel_launch(void* const* d_in, const int* in_sizes, int n_in,
                              void* d_out, int out_size, void* d_ws, size_t ws_size,
                              hipStream_t stream) {
    const float* x     = (const float*)d_in[0];
    const int* cluster = (const int*)d_in[1];
    // d_in[2] = batch (unused by the reference output)
    const float* W1    = (const float*)d_in[3];
    const float* b1    = (const float*)d_in[4];
    const float* ln_g  = (const float*)d_in[5];
    const float* ln_b  = (const float*)d_in[6];
    const float* W2    = (const float*)d_in[7];
    const float* b2    = (const float*)d_in[8];
    float* out = (float*)d_out;

    unsigned* aggr = (unsigned*)d_ws;                           // 6.4 MB
    unsigned short* w1f = (unsigned short*)((char*)d_ws + (size_t)NUM_CLUSTERS * 32 * 4);
    unsigned short* w2f = w1f + 8 * 64 * 8;                     // +8 KB, then +4 KB

    int N = in_sizes[0] / 64;

    hipMemsetAsync(aggr, 0, (size_t)NUM_CLUSTERS * 32 * sizeof(unsigned), stream);
    prep_weights<<<3, 256, 0, stream>>>(W1, W2, w1f, w2f);

    int blocks1 = (N + 255) / 256;
    mlp_segmax_kernel<<<blocks1, 256, 0, stream>>>(
        x, cluster, w1f, b1, ln_g, ln_b, w2f, b2, out, aggr, N);

    long long total2 = (long long)N * 8;
    int blocks2 = (int)((total2 + 255) / 256);
    gather_kernel<<<blocks2, 256, 0, stream>>>(cluster, aggr, out, N);
}

// Round 5
// 271.611 us; speedup vs baseline: 5.2888x; 1.0812x over previous
//
#include <hip/hip_runtime.h>
#include <hip/hip_bf16.h>

#define NUM_CLUSTERS 50000

typedef __attribute__((ext_vector_type(8))) short bfx8;
typedef __attribute__((ext_vector_type(4))) float f32x4;

// Monotonic unsigned mapping of f32: preserves order, atomicMax-able.
__device__ __forceinline__ unsigned fkey(float f) {
    unsigned b = __float_as_uint(f);
    return b ^ ((b & 0x80000000u) ? 0xFFFFFFFFu : 0x80000000u);
}
__device__ __forceinline__ float funkey(unsigned k) {
    unsigned b = (k & 0x80000000u) ? (k ^ 0x80000000u) : ~k;
    return __uint_as_float(b);
}
__device__ __forceinline__ unsigned short f2bf(float f) {  // RNE
    unsigned u = __float_as_uint(f);
    return (unsigned short)((u + 0x7FFFu + ((u >> 16) & 1u)) >> 16);
}
__device__ __forceinline__ unsigned pk2bf(float a, float b) {  // packed RNE pair
    __hip_bfloat162 h = __float22bfloat162_rn(make_float2(a, b));
    return *(unsigned*)&h;
}

// One-time per-launch weight repack into MFMA B-fragment order (bf16).
// B-frag for mfma_f32_16x16x32_bf16: lane holds B[k0..k0+7][col],
// col = 16*ct + (lane&15), k0 = kb*32 + (lane>>4)*8.
__global__ __launch_bounds__(256) void prep_weights(
    const float* __restrict__ W1, const float* __restrict__ W2,
    unsigned short* __restrict__ w1f, unsigned short* __restrict__ w2f)
{
    int tid = blockIdx.x * 256 + threadIdx.x;
    if (tid < 512) {                       // W1: 4 col-tiles x 2 k-frags
        int frag = tid >> 6, lane = tid & 63;
        int ct = frag >> 1, kb = frag & 1;
        int col = ct * 16 + (lane & 15);
        int k0 = kb * 32 + (lane >> 4) * 8;
        #pragma unroll
        for (int i = 0; i < 8; ++i)
            w1f[(frag * 64 + lane) * 8 + i] = f2bf(W1[(k0 + i) * 64 + col]);
    } else if (tid < 768) {                // W2: 2 col-tiles x 2 k-frags
        int frag = (tid - 512) >> 6, lane = tid & 63;
        int ct = frag >> 1, kb = frag & 1;
        int col = ct * 16 + (lane & 15);
        int k0 = kb * 32 + (lane >> 4) * 8;
        #pragma unroll
        for (int i = 0; i < 8; ++i)
            w2f[(frag * 64 + lane) * 8 + i] = f2bf(W2[(k0 + i) * 32 + col]);
    }
}

// Block = 256 threads = 4 INDEPENDENT waves (no __syncthreads anywhere).
// Wave w owns nodes [blockBase + w*64, +64) and an 8 KB LDS quadrant.
// Stage x coalesced->bf16 LDS (XOR-swizzled 16B granules = A-frag order);
// per 16-node group: MFMA GEMM1 -> LN+SiLU (width-16 shuffles) -> h back to
// the group's own LDS rows -> MFMA GEMM2 -> o back to the (now dead) same
// rows -> batched stale-read-filtered segment-max atomics from registers.
// After all groups: wave-local coalesced full-line nt stores of out[:, :32].
__global__ __launch_bounds__(256, 5) void mlp_segmax_kernel(
    const float* __restrict__ x, const int* __restrict__ cluster,
    const unsigned short* __restrict__ w1f, const float* __restrict__ b1,
    const float* __restrict__ ln_g, const float* __restrict__ ln_b,
    const unsigned short* __restrict__ w2f, const float* __restrict__ b2,
    float* __restrict__ out, unsigned* __restrict__ aggr, int N)
{
    __shared__ char smem[256 * 128];       // 4 waves x 8 KB quadrants
    const int t = threadIdx.x;
    const int lane = t & 63;
    const int w = t >> 6;
    const int l15 = lane & 15;
    const int q = lane >> 4;
    const long long wbase = (long long)blockIdx.x * 256 + w * 64;  // first node of wave
    if (wbase >= N) return;                // whole-wave early exit (N % 64 == 0)
    char* wmem = smem + w * 8192;

    // ---- Stage: wave-private coalesced x load -> bf16 LDS (swizzled granules)
    #pragma unroll 4
    for (int p = 0; p < 16; ++p) {
        int le = (p * 64 + lane) * 4;      // elem 0..4095 within wave tile
        float4 v = *(const float4*)(x + wbase * 64 + le);
        int row = le >> 6;                 // 0..63
        int k = le & 63;
        int g = k >> 3;
        int half = (k >> 2) & 1;
        int phys = row * 128 + ((g ^ (row & 7)) << 4) + (half << 3);
        *(uint2*)(wmem + phys) = make_uint2(pk2bf(v.x, v.y), pk2bf(v.z, v.w));
    }

    // weight fragments (lane-indexed, L2-hot, reused across all 4 groups)
    bfx8 W1F[4][2], W2F[2][2];
    #pragma unroll
    for (int ct = 0; ct < 4; ++ct)
        #pragma unroll
        for (int kb = 0; kb < 2; ++kb)
            W1F[ct][kb] = *(const bfx8*)(w1f + ((ct * 2 + kb) * 64 + lane) * 8);
    #pragma unroll
    for (int ct = 0; ct < 2; ++ct)
        #pragma unroll
        for (int kb = 0; kb < 2; ++kb)
            W2F[ct][kb] = *(const bfx8*)(w2f + ((ct * 2 + kb) * 64 + lane) * 8);

    // per-lane column params (col = 16*tt + l15)
    float g4[4], bb4[4], b1c[4];
    #pragma unroll
    for (int tt = 0; tt < 4; ++tt) {
        g4[tt]  = ln_g[16 * tt + l15];
        bb4[tt] = ln_b[16 * tt + l15];
        b1c[tt] = b1[16 * tt + l15];
    }
    float b2c[2] = { b2[l15], b2[16 + l15] };

    // ---- 4 groups of 16 nodes
    #pragma unroll 1
    for (int g = 0; g < 4; ++g) {
        const int base = g * 16;           // local row base
        const int arow = base + l15;
        const int arsw = arow & 7;

        // A-frags: lane reads x[arow][k0..k0+7], k0 = kb*32 + q*8
        bfx8 af[2];
        #pragma unroll
        for (int kb = 0; kb < 2; ++kb)
            af[kb] = *(const bfx8*)(wmem + arow * 128 + (((kb * 4 + q) ^ arsw) << 4));

        // GEMM1
        f32x4 acc[4];
        #pragma unroll
        for (int tt = 0; tt < 4; ++tt) {
            float b = b1c[tt];
            acc[tt] = (f32x4){b, b, b, b};
        }
        #pragma unroll
        for (int kb = 0; kb < 2; ++kb)
            #pragma unroll
            for (int tt = 0; tt < 4; ++tt)
                acc[tt] = __builtin_amdgcn_mfma_f32_16x16x32_bf16(af[kb], W1F[tt][kb], acc[tt], 0, 0, 0);

        // LayerNorm: row q*4+r lives in the 16 lanes of quarter q
        float s[4];
        #pragma unroll
        for (int r = 0; r < 4; ++r)
            s[r] = acc[0][r] + acc[1][r] + acc[2][r] + acc[3][r];
        #pragma unroll
        for (int m = 1; m < 16; m <<= 1)
            #pragma unroll
            for (int r = 0; r < 4; ++r) s[r] += __shfl_xor(s[r], m, 16);
        float mu[4];
        #pragma unroll
        for (int r = 0; r < 4; ++r) mu[r] = s[r] * (1.f / 64.f);
        float vv[4] = {0.f, 0.f, 0.f, 0.f};
        #pragma unroll
        for (int tt = 0; tt < 4; ++tt)
            #pragma unroll
            for (int r = 0; r < 4; ++r) {
                float d = acc[tt][r] - mu[r];
                vv[r] = fmaf(d, d, vv[r]);
            }
        #pragma unroll
        for (int m = 1; m < 16; m <<= 1)
            #pragma unroll
            for (int r = 0; r < 4; ++r) vv[r] += __shfl_xor(vv[r], m, 16);
        float rs[4];
        #pragma unroll
        for (int r = 0; r < 4; ++r) rs[r] = rsqrtf(vv[r] * (1.f / 64.f) + 1e-5f);

        // affine + SiLU, pack bf16, write h rows (own wave's rows, DS in-order)
        #pragma unroll
        for (int tt = 0; tt < 4; ++tt)
            #pragma unroll
            for (int r = 0; r < 4; ++r) {
                float val = (acc[tt][r] - mu[r]) * rs[r] * g4[tt] + bb4[tt];
                val = val / (1.f + __expf(-val));   // SiLU
                int node = base + q * 4 + r;
                int col = 16 * tt + l15;
                int phys = node * 128 + ((((col >> 3)) ^ (node & 7)) << 4) + ((col & 7) * 2);
                *(unsigned short*)(wmem + phys) = f2bf(val);
            }

        // GEMM2 A-frags from h (same rows, same wave -> ordered)
        bfx8 hf[2];
        #pragma unroll
        for (int kb = 0; kb < 2; ++kb)
            hf[kb] = *(const bfx8*)(wmem + arow * 128 + (((kb * 4 + q) ^ arsw) << 4));
        f32x4 oacc[2];
        #pragma unroll
        for (int c = 0; c < 2; ++c) {
            float b = b2c[c];
            oacc[c] = (f32x4){b, b, b, b};
        }
        #pragma unroll
        for (int kb = 0; kb < 2; ++kb)
            #pragma unroll
            for (int c = 0; c < 2; ++c)
                oacc[c] = __builtin_amdgcn_mfma_f32_16x16x32_bf16(hf[kb], W2F[c][kb], oacc[c], 0, 0, 0);

        // o -> the group's now-dead LDS rows, f32 [16][32], swizzled granules
        #pragma unroll
        for (int c = 0; c < 2; ++c)
            #pragma unroll
            for (int r = 0; r < 4; ++r) {
                int node = base + q * 4 + r;
                int byte = (c * 16 + l15) * 4;     // 0..127
                int phys = node * 128 + (((byte >> 4) ^ (node & 7)) << 4) + (byte & 15);
                *(float*)(wmem + phys) = oacc[c][r];
            }

        // batched stale-read-filtered segment-max atomics from registers.
        // Safe: slot values only grow within a launch; stale read <= current,
        // so skipping when stale >= candidate implies current >= candidate.
        int clr[4];
        #pragma unroll
        for (int r = 0; r < 4; ++r)
            clr[r] = cluster[wbase + base + q * 4 + r];
        unsigned keys[8];
        unsigned* slots[8];
        #pragma unroll
        for (int c = 0; c < 2; ++c)
            #pragma unroll
            for (int r = 0; r < 4; ++r) {
                int i = c * 4 + r;
                keys[i] = fkey(oacc[c][r]);
                slots[i] = aggr + (long long)clr[r] * 32 + c * 16 + l15;
            }
        unsigned olds[8];
        #pragma unroll
        for (int i = 0; i < 8; ++i) olds[i] = *slots[i];   // batched, in flight
        #pragma unroll
        for (int i = 0; i < 8; ++i)
            if (keys[i] > olds[i]) atomicMax(slots[i], keys[i]);
    }

    // ---- Wave-local coalesced full-line stores of out[:, 0:32] (nt hint)
    #pragma unroll 2
    for (int p = 0; p < 8; ++p) {
        int le = (p * 64 + lane) * 4;      // f32 elem within [64][32] o-tile
        int row = le >> 5;                 // 0..63
        int c = le & 31;                   // multiple of 4
        f32x4 v4 = *(const f32x4*)(wmem + row * 128 + (((c >> 2) ^ (row & 7)) << 4));
        __builtin_nontemporal_store(v4, (f32x4*)(out + (wbase + row) * 64 + c));
    }
}

// Gather: thread handles 4 cols -> out[n, 32+4k..] = decode(aggr[cluster[n]])
__global__ __launch_bounds__(256) void gather_kernel(
    const int* __restrict__ cluster, const unsigned* __restrict__ aggr,
    float* __restrict__ out, int N)
{
    long long idx = (long long)blockIdx.x * 256 + threadIdx.x;
    if (idx >= (long long)N * 8) return;
    int n = (int)(idx >> 3);
    int k4 = (int)(idx & 7) * 4;
    int c = cluster[n];
    uint4 a = *(const uint4*)(aggr + (size_t)c * 32 + k4);
    f32x4 o = {funkey(a.x), funkey(a.y), funkey(a.z), funkey(a.w)};
    __builtin_nontemporal_store(o, (f32x4*)(out + (size_t)n * 64 + 32 + k4));
}

extern "C" void kernel_launch(void* const* d_in, const int* in_sizes, int n_in,
                              void* d_out, int out_size, void* d_ws, size_t ws_size,
                              hipStream_t stream) {
    const float* x     = (const float*)d_in[0];
    const int* cluster = (const int*)d_in[1];
    // d_in[2] = batch (unused by the reference output)
    const float* W1    = (const float*)d_in[3];
    const float* b1    = (const float*)d_in[4];
    const float* ln_g  = (const float*)d_in[5];
    const float* ln_b  = (const float*)d_in[6];
    const float* W2    = (const float*)d_in[7];
    const float* b2    = (const float*)d_in[8];
    float* out = (float*)d_out;

    unsigned* aggr = (unsigned*)d_ws;                           // 6.4 MB
    unsigned short* w1f = (unsigned short*)((char*)d_ws + (size_t)NUM_CLUSTERS * 32 * 4);
    unsigned short* w2f = w1f + 8 * 64 * 8;                     // +8 KB, then +4 KB

    int N = in_sizes[0] / 64;

    hipMemsetAsync(aggr, 0, (size_t)NUM_CLUSTERS * 32 * sizeof(unsigned), stream);
    prep_weights<<<3, 256, 0, stream>>>(W1, W2, w1f, w2f);

    int blocks1 = (N + 255) / 256;
    mlp_segmax_kernel<<<blocks1, 256, 0, stream>>>(
        x, cluster, w1f, b1, ln_g, ln_b, w2f, b2, out, aggr, N);

    long long total2 = (long long)N * 8;
    int blocks2 = (int)((total2 + 255) / 256);
    gather_kernel<<<blocks2, 256, 0, stream>>>(cluster, aggr, out, N);
}